// Round 5
// baseline (585.805 us; speedup 1.0000x reference)
//
#include <hip/hip_runtime.h>

#define NCOMP 19
#define NB    4096
#define PI_F  3.14159265358979323846f

__device__ __forceinline__ void derivf(const float* __restrict__ y, float a, float bin,
                                       float* __restrict__ k) {
#pragma unroll
  for (int j = 0; j < NCOMP; ++j) {
    float s = -2.0f * y[j];
    if (j > 0) s += y[j - 1];
    if (j < NCOMP - 1) s += y[j + 1];
    k[j] = a * s;
  }
  k[NCOMP - 1] += bin;
}

__device__ __forceinline__ void rk4f(float* __restrict__ x, float a, float bin) {
  const float h = 0.01f, h2 = 0.005f, h6 = 0.01f / 6.0f;
  float k[NCOMP], y[NCOMP], acc[NCOMP];
  derivf(x, a, bin, k);
#pragma unroll
  for (int j = 0; j < NCOMP; ++j) { acc[j] = k[j]; y[j] = fmaf(h2, k[j], x[j]); }
  derivf(y, a, bin, k);
#pragma unroll
  for (int j = 0; j < NCOMP; ++j) { acc[j] = fmaf(2.0f, k[j], acc[j]); y[j] = fmaf(h2, k[j], x[j]); }
  derivf(y, a, bin, k);
#pragma unroll
  for (int j = 0; j < NCOMP; ++j) { acc[j] = fmaf(2.0f, k[j], acc[j]); y[j] = fmaf(h, k[j], x[j]); }
  derivf(y, a, bin, k);
#pragma unroll
  for (int j = 0; j < NCOMP; ++j) x[j] = fmaf(h6, acc[j] + k[j], x[j]);
}

// one 256-thread block = 2 batches x 2 systems; one WAVE per (batch,sys);
// each lane owns 16 consecutive timesteps.
__global__ __launch_bounds__(256) void spm_fused(
    const float* __restrict__ xin, const float* __restrict__ iseq,
    const float* __restrict__ An, const float* __restrict__ Bn,
    const float* __restrict__ Ap, const float* __restrict__ Bp,
    float* __restrict__ out)
{
  __shared__ __align__(16) float Vs[NCOMP][20];   // eigenvectors, rows padded to 16B
  __shared__ float xs0r[2][2][NCOMP];             // [bb][sys][j] initial states
  __shared__ float4 mcv[2][NCOMP];                // [sys][k]: (gi, w*gi, log2 g, -)
  __shared__ float sS0[2][2][NCOMP];              // [bb][sys][k] modal initial coords

  const int t = threadIdx.x;
  const int lane = t & 63;
  const int wid = t >> 6;          // 0..3
  const int bb = wid >> 1, sys = wid & 1;
  const int b = blockIdx.x * 2 + bb;

  const float alpha = sys ? Ap[1] : An[1];
  const float ab    = sys ? Bp[NCOMP - 1] : Bn[NCOMP - 1];

  // V[k][j] = sin((k+1)(j+1)pi/20)/sqrt(10)  (symmetric orthonormal)
  for (int idx = t; idx < NCOMP * 20; idx += 256) {
    int k = idx / 20, j = idx % 20;
    int m = ((k + 1) * (j + 1)) % 40;
    Vs[k][j] = (j < NCOMP) ? sinf((float)m * (PI_F / 20.0f)) * 0.31622776601683794f : 0.0f;
  }
  if (t < 76) {
    int lb = t / 38, rem = t % 38;
    xs0r[lb][rem / 19][rem % 19] = xin[(size_t)(blockIdx.x * 2 + lb) * 38 + rem];
  }
  __syncthreads();

  if (t < 38) {
    int sy = t / 19, k = t % 19;
    float al  = sy ? Ap[1] : An[1];
    float abv = sy ? Bp[NCOMP - 1] : Bn[NCOMP - 1];
    float sk = sinf((float)(k + 1) * (PI_F / 40.0f));
    float z  = 0.01f * al * (-4.0f * sk * sk);          // h*alpha*lambda_k
    float g  = 1.0f + z * (1.0f + z * (0.5f + z * ((1.0f/6.0f) + z * (1.0f/24.0f))));
    float S  = 1.0f + z * (0.5f + z * ((1.0f/6.0f) + z * (1.0f/24.0f)));
    float gi = 1.0f / g;
    mcv[sy][k] = make_float4(gi, 0.01f * S * abv * Vs[k][NCOMP - 1] * gi,
                             __builtin_log2f(g), 0.0f);
  }
  if (t < 76) {
    int lb = t / 38, rem = t % 38, sy = rem / 19, k = rem % 19;
    float s0 = 0.0f;
#pragma unroll
    for (int j = 0; j < NCOMP; ++j) s0 = fmaf(Vs[k][j], xs0r[lb][sy][j], s0);
    sS0[lb][sy][k] = s0;
  }
  __syncthreads();

  // 16 inputs per lane, kept in registers (4x dwordx4)
  float iv[16];
  const float* ib = iseq + (size_t)b * 1024 + lane * 16;
#pragma unroll
  for (int q = 0; q < 4; ++q) {
    float4 v = *reinterpret_cast<const float4*>(ib + q * 4);
    iv[4*q+0] = v.x; iv[4*q+1] = v.y; iv[4*q+2] = v.z; iv[4*q+3] = v.w;
  }

  const float t16 = (float)(lane * 16);

  // Phase A: per-mode weighted wave-exclusive prefix (no barriers)
  float Cp[NCOMP];
#pragma unroll
  for (int k = 0; k < NCOMP; ++k) {
    const float4 c = mcv[sys][k];
    float r = iv[15];
#pragma unroll
    for (int u = 14; u >= 0; --u) r = fmaf(r, c.x, iv[u]);   // sum g^{-v} i_v
    float e = t16 * c.z;
    float a = __builtin_exp2f(-e) * r;                       // g^{-16*lane} * r
    float v = a;
#pragma unroll
    for (int d = 1; d < 64; d <<= 1) {
      float o = __shfl_up(v, d);
      if (lane >= d) v += o;
    }
    Cp[k] = v - a;                                           // exclusive prefix
  }

  // Phase B: modal coord at this lane's start step -> physical state x0
  float x0[20];
#pragma unroll
  for (int j = 0; j < 20; ++j) x0[j] = 0.0f;
#pragma unroll
  for (int k = 0; k < NCOMP; ++k) {
    const float4 c = mcv[sys][k];
    float s = __builtin_exp2f(t16 * c.z) * fmaf(c.y, Cp[k], sS0[bb][sys][k]);
    const float4* vr = reinterpret_cast<const float4*>(&Vs[k][0]);
#pragma unroll
    for (int q = 0; q < 5; ++q) {
      float4 vv = vr[q];
      x0[4*q+0] = fmaf(s, vv.x, x0[4*q+0]);
      x0[4*q+1] = fmaf(s, vv.y, x0[4*q+1]);
      x0[4*q+2] = fmaf(s, vv.z, x0[4*q+2]);
      x0[4*q+3] = fmaf(s, vv.w, x0[4*q+3]);
    }
  }
  if (lane == 0) {   // exact initial state (no reconstruction error at t=0)
#pragma unroll
    for (int j = 0; j < NCOMP; ++j) x0[j] = xs0r[bb][sys][j];
  }

  // Emit: 4 rounds of 4 RK4 steps, float4 store per component per round.
  float* orow = out + ((size_t)b * (2 * NCOMP) + sys * NCOMP) * 1024 + lane * 16;
  float b0[NCOMP], b1[NCOMP], b2[NCOMP], b3[NCOMP];
  for (int rr = 0; rr < 4; ++rr) {
    rk4f(x0, alpha, iv[rr*4+0] * ab);
#pragma unroll
    for (int j = 0; j < NCOMP; ++j) b0[j] = x0[j];
    rk4f(x0, alpha, iv[rr*4+1] * ab);
#pragma unroll
    for (int j = 0; j < NCOMP; ++j) b1[j] = x0[j];
    rk4f(x0, alpha, iv[rr*4+2] * ab);
#pragma unroll
    for (int j = 0; j < NCOMP; ++j) b2[j] = x0[j];
    rk4f(x0, alpha, iv[rr*4+3] * ab);
#pragma unroll
    for (int j = 0; j < NCOMP; ++j) b3[j] = x0[j];
#pragma unroll
    for (int j = 0; j < NCOMP; ++j) {
      *reinterpret_cast<float4*>(orow + (size_t)j * 1024 + rr * 4) =
          make_float4(b0[j], b1[j], b2[j], b3[j]);
    }
  }
}

extern "C" void kernel_launch(void* const* d_in, const int* in_sizes, int n_in,
                              void* d_out, int out_size, void* d_ws, size_t ws_size,
                              hipStream_t stream) {
  const float* x    = (const float*)d_in[0];
  const float* iseq = (const float*)d_in[1];
  const float* An   = (const float*)d_in[2];
  const float* Bn   = (const float*)d_in[3];
  const float* Ap   = (const float*)d_in[4];
  const float* Bp   = (const float*)d_in[5];
  float* out = (float*)d_out;

  spm_fused<<<NB / 2, 256, 0, stream>>>(x, iseq, An, Bn, Ap, Bp, out);
}

// Round 6
// 178.498 us; speedup vs baseline: 3.2819x; 3.2819x over previous
//
#include <hip/hip_runtime.h>

#define NCOMP 19
#define NB    4096
#define PI_F  3.14159265358979323846f

// reference-identical RK4 (used once per thread to get the input-response vector d)
__device__ __forceinline__ void derivf(const float* __restrict__ y, float a, float bin,
                                       float* __restrict__ k) {
#pragma unroll
  for (int j = 0; j < NCOMP; ++j) {
    float s = -2.0f * y[j];
    if (j > 0) s += y[j - 1];
    if (j < NCOMP - 1) s += y[j + 1];
    k[j] = a * s;
  }
  k[NCOMP - 1] += bin;
}

__device__ __forceinline__ void rk4f(float* __restrict__ x, float a, float bin) {
  const float h = 0.01f, h2 = 0.005f, h6 = 0.01f / 6.0f;
  float k[NCOMP], y[NCOMP], acc[NCOMP];
  derivf(x, a, bin, k);
#pragma unroll
  for (int j = 0; j < NCOMP; ++j) { acc[j] = k[j]; y[j] = fmaf(h2, k[j], x[j]); }
  derivf(y, a, bin, k);
#pragma unroll
  for (int j = 0; j < NCOMP; ++j) { acc[j] = fmaf(2.0f, k[j], acc[j]); y[j] = fmaf(h2, k[j], x[j]); }
  derivf(y, a, bin, k);
#pragma unroll
  for (int j = 0; j < NCOMP; ++j) { acc[j] = fmaf(2.0f, k[j], acc[j]); y[j] = fmaf(h, k[j], x[j]); }
  derivf(y, a, bin, k);
#pragma unroll
  for (int j = 0; j < NCOMP; ++j) x[j] = fmaf(h6, acc[j] + k[j], x[j]);
}

// one tridiagonal apply: out = c * T * in,  T = tridiag(1,-2,1)
__device__ __forceinline__ void trid_apply(float c, const float* __restrict__ in,
                                           float* __restrict__ out) {
  out[0] = c * fmaf(-2.0f, in[0], in[1]);
#pragma unroll
  for (int j = 1; j < NCOMP - 1; ++j)
    out[j] = c * fmaf(-2.0f, in[j], in[j - 1] + in[j + 1]);
  out[NCOMP - 1] = c * fmaf(-2.0f, in[NCOMP - 1], in[NCOMP - 2]);
}

// one time step: x <- R4(h*alpha*T) x + i*d   (Horner; algebraically == RK4 step)
__device__ __forceinline__ void step_horner(float* __restrict__ x, float ha,
                                            const float4 d, float iin) {
  float w[NCOMP], t[NCOMP];
  trid_apply(ha * 0.25f, x, w);
#pragma unroll
  for (int j = 0; j < NCOMP; ++j) t[j] = x[j] + w[j];
  trid_apply(ha * (1.0f / 3.0f), t, w);
#pragma unroll
  for (int j = 0; j < NCOMP; ++j) t[j] = x[j] + w[j];
  trid_apply(ha * 0.5f, t, w);
#pragma unroll
  for (int j = 0; j < NCOMP; ++j) t[j] = x[j] + w[j];
  trid_apply(ha, t, w);
#pragma unroll
  for (int j = 0; j < NCOMP; ++j) x[j] = x[j] + w[j];
  x[15] = fmaf(iin, d.x, x[15]);
  x[16] = fmaf(iin, d.y, x[16]);
  x[17] = fmaf(iin, d.z, x[17]);
  x[18] = fmaf(iin, d.w, x[18]);
}

// one block (4 waves) = one (batch, system); thread t owns steps 4t..4t+3.
// wave-local scans, one barrier for cross-quarter prefix fixup.
__global__ __launch_bounds__(256) void spm_fused(
    const float* __restrict__ xin, const float* __restrict__ iseq,
    const float* __restrict__ An, const float* __restrict__ Bn,
    const float* __restrict__ Ap, const float* __restrict__ Bp,
    float* __restrict__ out)
{
  __shared__ __align__(16) float Vs[NCOMP][20];   // eigenvector rows (symmetric V)
  __shared__ float xs0[NCOMP];
  __shared__ float4 mcv[NCOMP];                   // (gi, w*gi, log2 g, s0)
  __shared__ __align__(16) float wtot[NCOMP][4];  // per-wave scan totals

  const int t = threadIdx.x;
  const int lane = t & 63, wid = t >> 6;
  const int b = blockIdx.x >> 1, sys = blockIdx.x & 1;
  const float alpha = sys ? Ap[1] : An[1];
  const float ab    = sys ? Bp[NCOMP - 1] : Bn[NCOMP - 1];
  const float ha    = 0.01f * alpha;

  // V[k][j] = sin((k+1)(j+1)pi/20)/sqrt(10)
  for (int idx = t; idx < NCOMP * 20; idx += 256) {
    int k = idx / 20, j = idx % 20;
    int m = ((k + 1) * (j + 1)) % 40;
    Vs[k][j] = (j < NCOMP) ? sinf((float)m * (PI_F / 20.0f)) * 0.31622776601683794f : 0.0f;
  }
  if (t < NCOMP) xs0[t] = xin[(size_t)b * (2 * NCOMP) + sys * NCOMP + t];
  __syncthreads();

  if (t < NCOMP) {
    float sk = sinf((float)(t + 1) * (PI_F / 40.0f));
    float z  = ha * (-4.0f * sk * sk);            // h*alpha*lambda_k
    float g  = 1.0f + z * (1.0f + z * (0.5f + z * ((1.0f/6.0f) + z * (1.0f/24.0f))));
    float S  = 1.0f + z * (0.5f + z * ((1.0f/6.0f) + z * (1.0f/24.0f)));
    float gi = 1.0f / g;
    float s0 = 0.0f;
#pragma unroll
    for (int j = 0; j < NCOMP; ++j) s0 = fmaf(Vs[t][j], xs0[j], s0);
    mcv[t] = make_float4(gi, 0.01f * S * ab * Vs[t][NCOMP - 1] * gi,
                         __builtin_log2f(g), s0);
  }
  __syncthreads();

  // input-response vector d = RK4 step from zero state with unit input
  float4 dvec;
  {
    float z[NCOMP];
#pragma unroll
    for (int j = 0; j < NCOMP; ++j) z[j] = 0.0f;
    rk4f(z, alpha, ab);
    dvec = make_float4(z[15], z[16], z[17], z[18]);
  }

  // this thread's 4 inputs
  const float4 iv = *reinterpret_cast<const float4*>(iseq + (size_t)b * 1024 + t * 4);
  const float pos = (float)(4 * t);

  // Phase A: per-mode weighted wave-local scan
  float Cp[NCOMP], Em[NCOMP];
#pragma unroll
  for (int k = 0; k < NCOMP; ++k) {
    const float4 c = mcv[k];
    float r = iv.x + c.x * (iv.y + c.x * (iv.z + c.x * iv.w));
    float e = pos * c.z;
    Em[k] = e;
    float a = __builtin_exp2f(-e) * r;
    float v = a;
#pragma unroll
    for (int d = 1; d < 64; d <<= 1) {
      float o = __shfl_up(v, d);
      if (lane >= d) v += o;
    }
    if (lane == 63) wtot[k][wid] = v;
    Cp[k] = v - a;
  }
  __syncthreads();

  // Phase B: add cross-quarter offsets, reconstruct physical x0
  float x0[20];
#pragma unroll
  for (int j = 0; j < 20; ++j) x0[j] = 0.0f;
#pragma unroll
  for (int k = 0; k < NCOMP; ++k) {
    const float4 c = mcv[k];
    float4 q = *reinterpret_cast<const float4*>(&wtot[k][0]);
    float C = Cp[k];
    if (wid > 0) C += q.x;
    if (wid > 1) C += q.y;
    if (wid > 2) C += q.z;
    float s = __builtin_exp2f(Em[k]) * fmaf(c.y, C, c.w);
    const float4* vr = reinterpret_cast<const float4*>(&Vs[k][0]);
#pragma unroll
    for (int qq = 0; qq < 5; ++qq) {
      float4 vv = vr[qq];
      x0[4*qq+0] = fmaf(s, vv.x, x0[4*qq+0]);
      x0[4*qq+1] = fmaf(s, vv.y, x0[4*qq+1]);
      x0[4*qq+2] = fmaf(s, vv.z, x0[4*qq+2]);
      x0[4*qq+3] = fmaf(s, vv.w, x0[4*qq+3]);
    }
  }
  if (t == 0) {   // exact initial state at step 0
#pragma unroll
    for (int j = 0; j < NCOMP; ++j) x0[j] = xs0[j];
  }

  // 4 steps (Horner form), buffer, emit lane-contiguous float4 per component
  float b0[NCOMP], b1[NCOMP], b2[NCOMP], b3[NCOMP];
  step_horner(x0, ha, dvec, iv.x);
#pragma unroll
  for (int j = 0; j < NCOMP; ++j) b0[j] = x0[j];
  step_horner(x0, ha, dvec, iv.y);
#pragma unroll
  for (int j = 0; j < NCOMP; ++j) b1[j] = x0[j];
  step_horner(x0, ha, dvec, iv.z);
#pragma unroll
  for (int j = 0; j < NCOMP; ++j) b2[j] = x0[j];
  step_horner(x0, ha, dvec, iv.w);
#pragma unroll
  for (int j = 0; j < NCOMP; ++j) b3[j] = x0[j];

  float* orow = out + ((size_t)b * (2 * NCOMP) + sys * NCOMP) * 1024 + t * 4;
#pragma unroll
  for (int j = 0; j < NCOMP; ++j) {
    *reinterpret_cast<float4*>(orow + (size_t)j * 1024) =
        make_float4(b0[j], b1[j], b2[j], b3[j]);
  }
}

extern "C" void kernel_launch(void* const* d_in, const int* in_sizes, int n_in,
                              void* d_out, int out_size, void* d_ws, size_t ws_size,
                              hipStream_t stream) {
  const float* x    = (const float*)d_in[0];
  const float* iseq = (const float*)d_in[1];
  const float* An   = (const float*)d_in[2];
  const float* Bn   = (const float*)d_in[3];
  const float* Ap   = (const float*)d_in[4];
  const float* Bp   = (const float*)d_in[5];
  float* out = (float*)d_out;

  spm_fused<<<NB * 2, 256, 0, stream>>>(x, iseq, An, Bn, Ap, Bp, out);
}

// Round 8
// 160.143 us; speedup vs baseline: 3.6580x; 1.1146x over previous
//
#include <hip/hip_runtime.h>

#define NCOMP 19
#define NB    4096
#define PI_F  3.14159265358979323846f

typedef float f32x4 __attribute__((ext_vector_type(4)));

// reference-identical RK4 (setup only: input-response vector per system)
__device__ __forceinline__ void derivf(const float* __restrict__ y, float a, float bin,
                                       float* __restrict__ k) {
#pragma unroll
  for (int j = 0; j < NCOMP; ++j) {
    float s = -2.0f * y[j];
    if (j > 0) s += y[j - 1];
    if (j < NCOMP - 1) s += y[j + 1];
    k[j] = a * s;
  }
  k[NCOMP - 1] += bin;
}

__device__ __forceinline__ void rk4f(float* __restrict__ x, float a, float bin) {
  const float h = 0.01f, h2 = 0.005f, h6 = 0.01f / 6.0f;
  float k[NCOMP], y[NCOMP], acc[NCOMP];
  derivf(x, a, bin, k);
#pragma unroll
  for (int j = 0; j < NCOMP; ++j) { acc[j] = k[j]; y[j] = fmaf(h2, k[j], x[j]); }
  derivf(y, a, bin, k);
#pragma unroll
  for (int j = 0; j < NCOMP; ++j) { acc[j] = fmaf(2.0f, k[j], acc[j]); y[j] = fmaf(h2, k[j], x[j]); }
  derivf(y, a, bin, k);
#pragma unroll
  for (int j = 0; j < NCOMP; ++j) { acc[j] = fmaf(2.0f, k[j], acc[j]); y[j] = fmaf(h, k[j], x[j]); }
  derivf(y, a, bin, k);
#pragma unroll
  for (int j = 0; j < NCOMP; ++j) x[j] = fmaf(h6, acc[j] + k[j], x[j]);
}

// out = c * T * in,  T = tridiag(1,-2,1)
__device__ __forceinline__ void trid_apply(float c, const float* __restrict__ in,
                                           float* __restrict__ out) {
  out[0] = c * fmaf(-2.0f, in[0], in[1]);
#pragma unroll
  for (int j = 1; j < NCOMP - 1; ++j)
    out[j] = c * fmaf(-2.0f, in[j], in[j - 1] + in[j + 1]);
  out[NCOMP - 1] = c * fmaf(-2.0f, in[NCOMP - 1], in[NCOMP - 2]);
}

// x <- R4(h*alpha*T) x + i*d   (Horner; algebraically == one RK4 step)
__device__ __forceinline__ void step_horner(float* __restrict__ x, float ha,
                                            const float4 d, float iin) {
  float w[NCOMP], t[NCOMP];
  trid_apply(ha * 0.25f, x, w);
#pragma unroll
  for (int j = 0; j < NCOMP; ++j) t[j] = x[j] + w[j];
  trid_apply(ha * (1.0f / 3.0f), t, w);
#pragma unroll
  for (int j = 0; j < NCOMP; ++j) t[j] = x[j] + w[j];
  trid_apply(ha * 0.5f, t, w);
#pragma unroll
  for (int j = 0; j < NCOMP; ++j) t[j] = x[j] + w[j];
  trid_apply(ha, t, w);
#pragma unroll
  for (int j = 0; j < NCOMP; ++j) x[j] = x[j] + w[j];
  x[15] = fmaf(iin, d.x, x[15]);
  x[16] = fmaf(iin, d.y, x[16]);
  x[17] = fmaf(iin, d.z, x[17]);
  x[18] = fmaf(iin, d.w, x[18]);
}

// one block (4 waves) = one (batch, system); thread t owns steps 4t..4t+3.
__global__ __launch_bounds__(256) void spm_fused(
    const float* __restrict__ xin, const float* __restrict__ iseq,
    const float* __restrict__ An, const float* __restrict__ Bn,
    const float* __restrict__ Ap, const float* __restrict__ Bp,
    float* __restrict__ out)
{
  __shared__ __align__(16) float Vs[NCOMP][20];   // eigenvector rows (symmetric V)
  __shared__ float xs0[NCOMP];
  __shared__ float4 mcv[NCOMP];                   // (gi, w*gi, log2 g, s0)
  __shared__ __align__(16) float wtot[NCOMP][4];  // per-wave scan totals
  __shared__ float4 dls[2];                       // input-response vector per system

  const int t = threadIdx.x;
  const int lane = t & 63, wid = t >> 6;
  const int b = blockIdx.x >> 1, sys = blockIdx.x & 1;
  const float alpha = sys ? Ap[1] : An[1];
  const float ha    = 0.01f * alpha;

  // input-response vector d = RK4 step from zero state with unit input (2 threads)
  if (t < 2) {
    float al  = t ? Ap[1] : An[1];
    float abv = t ? Bp[NCOMP - 1] : Bn[NCOMP - 1];
    float z[NCOMP];
#pragma unroll
    for (int j = 0; j < NCOMP; ++j) z[j] = 0.0f;
    rk4f(z, al, abv);
    dls[t] = make_float4(z[15], z[16], z[17], z[18]);
  }

  // V[k][j] = sin((k+1)(j+1)pi/20)/sqrt(10)
  for (int idx = t; idx < NCOMP * 20; idx += 256) {
    int k = idx / 20, j = idx % 20;
    int m = ((k + 1) * (j + 1)) % 40;
    Vs[k][j] = (j < NCOMP) ? sinf((float)m * (PI_F / 20.0f)) * 0.31622776601683794f : 0.0f;
  }
  if (t < NCOMP) xs0[t] = xin[(size_t)b * (2 * NCOMP) + sys * NCOMP + t];
  __syncthreads();

  if (t < NCOMP) {
    float ab = sys ? Bp[NCOMP - 1] : Bn[NCOMP - 1];
    float sk = sinf((float)(t + 1) * (PI_F / 40.0f));
    float z  = ha * (-4.0f * sk * sk);            // h*alpha*lambda_k
    float g  = 1.0f + z * (1.0f + z * (0.5f + z * ((1.0f/6.0f) + z * (1.0f/24.0f))));
    float S  = 1.0f + z * (0.5f + z * ((1.0f/6.0f) + z * (1.0f/24.0f)));
    float gi = 1.0f / g;
    float s0 = 0.0f;
#pragma unroll
    for (int j = 0; j < NCOMP; ++j) s0 = fmaf(Vs[t][j], xs0[j], s0);
    mcv[t] = make_float4(gi, 0.01f * S * ab * Vs[t][NCOMP - 1] * gi,
                         __builtin_log2f(g), s0);
  }
  __syncthreads();

  const float4 dvec = dls[sys];
  const float4 iv = *reinterpret_cast<const float4*>(iseq + (size_t)b * 1024 + t * 4);
  const float pos = (float)(4 * t);

  // Phase A: per-mode weighted wave-local scan
  float Cp[NCOMP];
#pragma unroll
  for (int k = 0; k < NCOMP; ++k) {
    const float4 c = mcv[k];
    float r = iv.x + c.x * (iv.y + c.x * (iv.z + c.x * iv.w));
    float a = __builtin_exp2f(-pos * c.z) * r;
    float v = a;
#pragma unroll
    for (int d = 1; d < 64; d <<= 1) {
      float o = __shfl_up(v, d);
      if (lane >= d) v += o;
    }
    if (lane == 63) wtot[k][wid] = v;
    Cp[k] = v - a;
  }
  __syncthreads();

  // Phase B: add cross-quarter offsets, reconstruct physical x0
  float x0[20];
#pragma unroll
  for (int j = 0; j < 20; ++j) x0[j] = 0.0f;
#pragma unroll
  for (int k = 0; k < NCOMP; ++k) {
    const float4 c = mcv[k];
    float4 q = *reinterpret_cast<const float4*>(&wtot[k][0]);
    float C = Cp[k];
    if (wid > 0) C += q.x;
    if (wid > 1) C += q.y;
    if (wid > 2) C += q.z;
    float s = __builtin_exp2f(pos * c.z) * fmaf(c.y, C, c.w);
    const float4* vr = reinterpret_cast<const float4*>(&Vs[k][0]);
#pragma unroll
    for (int qq = 0; qq < 5; ++qq) {
      float4 vv = vr[qq];
      x0[4*qq+0] = fmaf(s, vv.x, x0[4*qq+0]);
      x0[4*qq+1] = fmaf(s, vv.y, x0[4*qq+1]);
      x0[4*qq+2] = fmaf(s, vv.z, x0[4*qq+2]);
      x0[4*qq+3] = fmaf(s, vv.w, x0[4*qq+3]);
    }
  }
  if (t == 0) {   // exact initial state at step 0
#pragma unroll
    for (int j = 0; j < NCOMP; ++j) x0[j] = xs0[j];
  }

  // 4 steps (Horner form), buffer, emit lane-contiguous nontemporal float4 per row
  float b0[NCOMP], b1[NCOMP], b2[NCOMP], b3[NCOMP];
  step_horner(x0, ha, dvec, iv.x);
#pragma unroll
  for (int j = 0; j < NCOMP; ++j) b0[j] = x0[j];
  step_horner(x0, ha, dvec, iv.y);
#pragma unroll
  for (int j = 0; j < NCOMP; ++j) b1[j] = x0[j];
  step_horner(x0, ha, dvec, iv.z);
#pragma unroll
  for (int j = 0; j < NCOMP; ++j) b2[j] = x0[j];
  step_horner(x0, ha, dvec, iv.w);
#pragma unroll
  for (int j = 0; j < NCOMP; ++j) b3[j] = x0[j];

  float* orow = out + ((size_t)b * (2 * NCOMP) + sys * NCOMP) * 1024 + t * 4;
#pragma unroll
  for (int j = 0; j < NCOMP; ++j) {
    f32x4 v = { b0[j], b1[j], b2[j], b3[j] };
    __builtin_nontemporal_store(v, reinterpret_cast<f32x4*>(orow + (size_t)j * 1024));
  }
}

extern "C" void kernel_launch(void* const* d_in, const int* in_sizes, int n_in,
                              void* d_out, int out_size, void* d_ws, size_t ws_size,
                              hipStream_t stream) {
  const float* x    = (const float*)d_in[0];
  const float* iseq = (const float*)d_in[1];
  const float* An   = (const float*)d_in[2];
  const float* Bn   = (const float*)d_in[3];
  const float* Ap   = (const float*)d_in[4];
  const float* Bp   = (const float*)d_in[5];
  float* out = (float*)d_out;

  spm_fused<<<NB * 2, 256, 0, stream>>>(x, iseq, An, Bn, Ap, Bp, out);
}

// Round 9
// 140.681 us; speedup vs baseline: 4.1641x; 1.1383x over previous
//
#include <hip/hip_runtime.h>

#define NCOMP 19
#define NB    4096
#define PI_F  3.14159265358979323846f

typedef float f32x4 __attribute__((ext_vector_type(4)));

// ---- compile-time eigenvector table: V[k][j] = sin((k+1)(j+1)pi/20)/sqrt(10) ----
__device__ __forceinline__ constexpr float vconst(int k, int j) {
  constexpr float S[21] = {
    0.0f, 0.15643446504023087f, 0.3090169943749474f, 0.45399049973954675f,
    0.5877852522924731f, 0.7071067811865476f, 0.8090169943749475f,
    0.8910065241883679f, 0.9510565162951535f, 0.9876883405951378f, 1.0f,
    0.9876883405951378f, 0.9510565162951535f, 0.8910065241883679f,
    0.8090169943749475f, 0.7071067811865476f, 0.5877852522924731f,
    0.45399049973954675f, 0.3090169943749474f, 0.15643446504023087f, 0.0f};
  int m = ((k + 1) * (j + 1)) % 40;
  float s = (m <= 20) ? S[m] : -S[m - 20];
  return s * 0.31622776601683794f;
}

// ---- DPP wave64 inclusive scan (VALU-only, no DS traffic) ----
template <int CTRL, int RMASK>
__device__ __forceinline__ float dpp_add(float x) {
  int v = __builtin_amdgcn_update_dpp(0, __float_as_int(x), CTRL, RMASK, 0xf, true);
  return x + __int_as_float(v);
}
__device__ __forceinline__ float wave_iscan(float x) {
  x = dpp_add<0x111, 0xf>(x);   // row_shr:1
  x = dpp_add<0x112, 0xf>(x);   // row_shr:2
  x = dpp_add<0x114, 0xf>(x);   // row_shr:4
  x = dpp_add<0x118, 0xf>(x);   // row_shr:8
  x = dpp_add<0x142, 0xa>(x);   // row_bcast:15 -> rows 1,3
  x = dpp_add<0x143, 0xc>(x);   // row_bcast:31 -> rows 2,3
  return x;
}

// reference-identical RK4 (setup only: input-response vector per system)
__device__ __forceinline__ void derivf(const float* __restrict__ y, float a, float bin,
                                       float* __restrict__ k) {
#pragma unroll
  for (int j = 0; j < NCOMP; ++j) {
    float s = -2.0f * y[j];
    if (j > 0) s += y[j - 1];
    if (j < NCOMP - 1) s += y[j + 1];
    k[j] = a * s;
  }
  k[NCOMP - 1] += bin;
}

__device__ __forceinline__ void rk4f(float* __restrict__ x, float a, float bin) {
  const float h = 0.01f, h2 = 0.005f, h6 = 0.01f / 6.0f;
  float k[NCOMP], y[NCOMP], acc[NCOMP];
  derivf(x, a, bin, k);
#pragma unroll
  for (int j = 0; j < NCOMP; ++j) { acc[j] = k[j]; y[j] = fmaf(h2, k[j], x[j]); }
  derivf(y, a, bin, k);
#pragma unroll
  for (int j = 0; j < NCOMP; ++j) { acc[j] = fmaf(2.0f, k[j], acc[j]); y[j] = fmaf(h2, k[j], x[j]); }
  derivf(y, a, bin, k);
#pragma unroll
  for (int j = 0; j < NCOMP; ++j) { acc[j] = fmaf(2.0f, k[j], acc[j]); y[j] = fmaf(h, k[j], x[j]); }
  derivf(y, a, bin, k);
#pragma unroll
  for (int j = 0; j < NCOMP; ++j) x[j] = fmaf(h6, acc[j] + k[j], x[j]);
}

// one Horner stage: o = x + c * T * u,  T = tridiag(1,-2,1)  (fused fma form)
__device__ __forceinline__ void stage(float c, const float* __restrict__ u,
                                      const float* __restrict__ x,
                                      float* __restrict__ o) {
  o[0] = fmaf(c, fmaf(-2.0f, u[0], u[1]), x[0]);
#pragma unroll
  for (int j = 1; j < NCOMP - 1; ++j)
    o[j] = fmaf(c, fmaf(-2.0f, u[j], u[j - 1] + u[j + 1]), x[j]);
  o[NCOMP - 1] = fmaf(c, fmaf(-2.0f, u[NCOMP - 1], u[NCOMP - 2]), x[NCOMP - 1]);
}

// x <- R4(h*alpha*T) x + i*d   (algebraically == one RK4 step)
__device__ __forceinline__ void step_horner(float* __restrict__ x, float ha,
                                            const float4 d, float iin) {
  float t1[NCOMP], t2[NCOMP];
  stage(ha * 0.25f, x, x, t1);
  stage(ha * (1.0f / 3.0f), t1, x, t2);
  stage(ha * 0.5f, t2, x, t1);
  stage(ha, t1, x, x);   // per-element: reads x[j] before writing x[j]; u=t1 separate
  x[15] = fmaf(iin, d.x, x[15]);
  x[16] = fmaf(iin, d.y, x[16]);
  x[17] = fmaf(iin, d.z, x[17]);
  x[18] = fmaf(iin, d.w, x[18]);
}

// one block (4 waves) = one (batch, system); thread t owns steps 4t..4t+3.
__global__ __launch_bounds__(256) void spm_fused(
    const float* __restrict__ xin, const float* __restrict__ iseq,
    const float* __restrict__ An, const float* __restrict__ Bn,
    const float* __restrict__ Ap, const float* __restrict__ Bp,
    float* __restrict__ out)
{
  __shared__ float xs0[NCOMP];
  __shared__ float4 mcv[NCOMP];                   // (gi, w*gi, log2 g, s0)
  __shared__ __align__(16) float wtot[NCOMP][4];  // per-wave scan totals
  __shared__ float4 dls[2];                       // input-response vector per system

  const int t = threadIdx.x;
  const int lane = t & 63, wid = t >> 6;
  const int b = blockIdx.x >> 1, sys = blockIdx.x & 1;
  const float alpha = sys ? Ap[1] : An[1];
  const float ha    = 0.01f * alpha;

  // input-response vector d = RK4 step from zero state with unit input (2 threads)
  if (t < 2) {
    float al  = t ? Ap[1] : An[1];
    float abv = t ? Bp[NCOMP - 1] : Bn[NCOMP - 1];
    float z[NCOMP];
#pragma unroll
    for (int j = 0; j < NCOMP; ++j) z[j] = 0.0f;
    rk4f(z, al, abv);
    dls[t] = make_float4(z[15], z[16], z[17], z[18]);
  }
  if (t < NCOMP) xs0[t] = xin[(size_t)b * (2 * NCOMP) + sys * NCOMP + t];
  __syncthreads();

  if (t < NCOMP) {
    float ab = sys ? Bp[NCOMP - 1] : Bn[NCOMP - 1];
    float sk = sinf((float)(t + 1) * (PI_F / 40.0f));
    float z  = ha * (-4.0f * sk * sk);            // h*alpha*lambda_k
    float g  = 1.0f + z * (1.0f + z * (0.5f + z * ((1.0f/6.0f) + z * (1.0f/24.0f))));
    float S  = 1.0f + z * (0.5f + z * ((1.0f/6.0f) + z * (1.0f/24.0f)));
    float gi = 1.0f / g;
    float vlast = sinf((float)(((t + 1) * NCOMP) % 40) * (PI_F / 20.0f)) *
                  0.31622776601683794f;
    float s0 = 0.0f;
#pragma unroll
    for (int j = 0; j < NCOMP; ++j)
      s0 = fmaf(sinf((float)(((t + 1) * (j + 1)) % 40) * (PI_F / 20.0f)) *
                    0.31622776601683794f, xs0[j], s0);
    mcv[t] = make_float4(gi, 0.01f * S * ab * vlast * gi, __builtin_log2f(g), s0);
  }
  __syncthreads();

  const float4 dvec = dls[sys];
  const float4 iv = *reinterpret_cast<const float4*>(iseq + (size_t)b * 1024 + t * 4);
  const float pos = (float)(4 * t);

  // Phase A: per-mode weighted wave-local scan (DPP, no DS)
  float Cp[NCOMP];
#pragma unroll
  for (int k = 0; k < NCOMP; ++k) {
    const float4 c = mcv[k];
    float r = iv.x + c.x * (iv.y + c.x * (iv.z + c.x * iv.w));
    float a = __builtin_exp2f(-pos * c.z) * r;
    float v = wave_iscan(a);
    if (lane == 63) wtot[k][wid] = v;
    Cp[k] = v - a;
  }
  __syncthreads();

  // Phase B: add cross-quarter offsets, reconstruct physical x0 (constants, no DS)
  float x0[NCOMP];
#pragma unroll
  for (int j = 0; j < NCOMP; ++j) x0[j] = 0.0f;
#pragma unroll
  for (int k = 0; k < NCOMP; ++k) {
    const float4 c = mcv[k];
    float4 q = *reinterpret_cast<const float4*>(&wtot[k][0]);
    float C = Cp[k];
    if (wid > 0) C += q.x;
    if (wid > 1) C += q.y;
    if (wid > 2) C += q.z;
    float s = __builtin_exp2f(pos * c.z) * fmaf(c.y, C, c.w);
#pragma unroll
    for (int j = 0; j < NCOMP; ++j) x0[j] = fmaf(s, vconst(k, j), x0[j]);
  }
  if (t == 0) {   // exact initial state at step 0
#pragma unroll
    for (int j = 0; j < NCOMP; ++j) x0[j] = xs0[j];
  }

  // 4 steps (Horner form), buffer, emit lane-contiguous nontemporal float4 per row
  float b0[NCOMP], b1[NCOMP], b2[NCOMP], b3[NCOMP];
  step_horner(x0, ha, dvec, iv.x);
#pragma unroll
  for (int j = 0; j < NCOMP; ++j) b0[j] = x0[j];
  step_horner(x0, ha, dvec, iv.y);
#pragma unroll
  for (int j = 0; j < NCOMP; ++j) b1[j] = x0[j];
  step_horner(x0, ha, dvec, iv.z);
#pragma unroll
  for (int j = 0; j < NCOMP; ++j) b2[j] = x0[j];
  step_horner(x0, ha, dvec, iv.w);
#pragma unroll
  for (int j = 0; j < NCOMP; ++j) b3[j] = x0[j];

  float* orow = out + ((size_t)b * (2 * NCOMP) + sys * NCOMP) * 1024 + t * 4;
#pragma unroll
  for (int j = 0; j < NCOMP; ++j) {
    f32x4 v = { b0[j], b1[j], b2[j], b3[j] };
    __builtin_nontemporal_store(v, reinterpret_cast<f32x4*>(orow + (size_t)j * 1024));
  }
}

extern "C" void kernel_launch(void* const* d_in, const int* in_sizes, int n_in,
                              void* d_out, int out_size, void* d_ws, size_t ws_size,
                              hipStream_t stream) {
  const float* x    = (const float*)d_in[0];
  const float* iseq = (const float*)d_in[1];
  const float* An   = (const float*)d_in[2];
  const float* Bn   = (const float*)d_in[3];
  const float* Ap   = (const float*)d_in[4];
  const float* Bp   = (const float*)d_in[5];
  float* out = (float*)d_out;

  spm_fused<<<NB * 2, 256, 0, stream>>>(x, iseq, An, Bn, Ap, Bp, out);
}